// Round 1
// baseline (313.089 us; speedup 1.0000x reference)
//
#include <hip/hip_runtime.h>
#include <hip/hip_bf16.h>

typedef __attribute__((ext_vector_type(8))) short bf16x8;   // 8 bf16 in 4 VGPRs
typedef __attribute__((ext_vector_type(4))) float f32x4;

#define B_ 2
#define S_ 2048
#define D_ 1024
#define H_ 16
#define DH_ 64

// round-to-nearest-even fp32 -> bf16 (all values finite here)
__device__ __forceinline__ unsigned short f2bf(float x) {
  unsigned u = __float_as_uint(x);
  unsigned r = (u + 0x7fffu + ((u >> 16) & 1u)) >> 16;
  return (unsigned short)r;
}

__device__ __forceinline__ void gload_lds16(const void* g, void* l) {
  __builtin_amdgcn_global_load_lds((const __attribute__((address_space(1))) void*)g,
                                   (__attribute__((address_space(3))) void*)l, 16, 0, 0);
}

// ---------------- fp32 -> bf16 convert (vectorized) ----------------
__global__ __launch_bounds__(256) void to_bf16_kernel(const float* __restrict__ x,
                                                      unsigned short* __restrict__ y, int n4) {
  int i = blockIdx.x * 256 + threadIdx.x;
  if (i >= n4) return;
  float4 v = ((const float4*)x)[i];
  ushort4 o;
  o.x = f2bf(v.x); o.y = f2bf(v.y); o.z = f2bf(v.z); o.w = f2bf(v.w);
  ((ushort4*)y)[i] = o;
}

// ---------------- fp32 [K][N] -> bf16 [N][K] transpose ----------------
__global__ __launch_bounds__(256) void transpose_bf16_kernel(const float* __restrict__ W,
                                                             unsigned short* __restrict__ WT) {
  __shared__ float tile[32][33];
  int r0 = blockIdx.y * 32, c0 = blockIdx.x * 32;
  int t = threadIdx.x;
  int lr = t >> 3, lc = (t & 7) * 4;
  float4 v = *(const float4*)&W[(size_t)(r0 + lr) * 1024 + c0 + lc];
  tile[lr][lc + 0] = v.x; tile[lr][lc + 1] = v.y; tile[lr][lc + 2] = v.z; tile[lr][lc + 3] = v.w;
  __syncthreads();
  ushort4 o;
  o.x = f2bf(tile[lc + 0][lr]);
  o.y = f2bf(tile[lc + 1][lr]);
  o.z = f2bf(tile[lc + 2][lr]);
  o.w = f2bf(tile[lc + 3][lr]);
  *(ushort4*)&WT[(size_t)(c0 + lr) * 1024 + r0 + lc] = o;
}

// ---------------- bf16 GEMM: C[M,N] = A[M,K] * BT[N,K]^T (+bias) ----------------
// 128x128 tile, BK=32, 4 waves each computing 64x64 via 4x4 frags of 16x16x32.
template<int FINAL>
__global__ __launch_bounds__(256) void gemm_bt(const unsigned short* __restrict__ A,
                                               const unsigned short* __restrict__ BT,
                                               const float* __restrict__ bias,
                                               void* __restrict__ Cout,
                                               int M, int N, int K) {
  __shared__ unsigned short As[128 * 32];
  __shared__ unsigned short Bs[128 * 32];
  const int t = threadIdx.x;
  const int w = t >> 6, l = t & 63;
  const int m0 = blockIdx.x * 128, n0 = blockIdx.y * 128;
  const int wm = (w >> 1) * 64, wn = (w & 1) * 64;
  const int lr = l & 15, lg = (l >> 4) * 8;
  f32x4 acc[4][4];
#pragma unroll
  for (int mi = 0; mi < 4; ++mi)
#pragma unroll
    for (int ni = 0; ni < 4; ++ni) acc[mi][ni] = {0.f, 0.f, 0.f, 0.f};

  for (int k0 = 0; k0 < K; k0 += 32) {
    __syncthreads();
#pragma unroll
    for (int it = 0; it < 2; ++it) {
      int o = t * 16 + it * 4096;          // byte offset in 8KB tile
      int row = o >> 6, ce = (o & 63) >> 1; // row, col in elems
      gload_lds16(A + (size_t)(m0 + row) * K + k0 + ce, (char*)As + w * 1024 + it * 4096);
      gload_lds16(BT + (size_t)(n0 + row) * K + k0 + ce, (char*)Bs + w * 1024 + it * 4096);
    }
    __syncthreads();
    bf16x8 af[4], bfr[4];
#pragma unroll
    for (int mi = 0; mi < 4; ++mi) af[mi] = *(const bf16x8*)&As[(wm + mi * 16 + lr) * 32 + lg];
#pragma unroll
    for (int ni = 0; ni < 4; ++ni) bfr[ni] = *(const bf16x8*)&Bs[(wn + ni * 16 + lr) * 32 + lg];
#pragma unroll
    for (int mi = 0; mi < 4; ++mi)
#pragma unroll
      for (int ni = 0; ni < 4; ++ni)
        acc[mi][ni] = __builtin_amdgcn_mfma_f32_16x16x32_bf16(af[mi], bfr[ni], acc[mi][ni], 0, 0, 0);
  }

  const int lg4 = (l >> 4) * 4;
#pragma unroll
  for (int mi = 0; mi < 4; ++mi)
#pragma unroll
    for (int ni = 0; ni < 4; ++ni) {
      int col = n0 + wn + ni * 16 + lr;
      float bv = FINAL ? bias[col] : 0.f;
#pragma unroll
      for (int j = 0; j < 4; ++j) {
        int row = m0 + wm + mi * 16 + lg4 + j;
        if (FINAL) ((float*)Cout)[(size_t)row * N + col] = acc[mi][ni][j] + bv;
        else       ((unsigned short*)Cout)[(size_t)row * N + col] = f2bf(acc[mi][ni][j]);
      }
    }
}

// ---------------- flash attention ----------------
// grid: (S/64, H, B); block 256 = 4 waves; wave w handles 16 q-rows.
__global__ __launch_bounds__(256) void attn_kernel(const unsigned short* __restrict__ Q,
                                                   const unsigned short* __restrict__ Kp,
                                                   const unsigned short* __restrict__ Vp,
                                                   unsigned short* __restrict__ O) {
  __shared__ unsigned short Klds[64][64];   // [kv][dh]
  __shared__ unsigned short Vlds[64][72];   // [dh][kv] transposed, padded
  __shared__ unsigned short Plds[4][16][64];
  const int t = threadIdx.x, w = t >> 6, l = t & 63;
  const int qt = blockIdx.x, h = blockIdx.y, b = blockIdx.z;
  const int lr = l & 15, lg = (l >> 4) * 8, lg4 = (l >> 4) * 4;
  const float c = 0.125f * 1.44269504089f;  // scale * log2(e)

  const size_t qrow = ((size_t)(b * S_ + qt * 64 + w * 16 + lr)) * 1024 + h * 64;
  bf16x8 qf0 = *(const bf16x8*)&Q[qrow + lg];
  bf16x8 qf1 = *(const bf16x8*)&Q[qrow + 32 + lg];

  f32x4 oacc[4];
#pragma unroll
  for (int i = 0; i < 4; ++i) oacc[i] = {0.f, 0.f, 0.f, 0.f};
  float m_run[4], l_run[4];
#pragma unroll
  for (int j = 0; j < 4; ++j) { m_run[j] = -1e30f; l_run[j] = 0.f; }

  const size_t kvbase = (size_t)b * S_ * 1024 + h * 64;
  for (int kv0 = 0; kv0 < S_; kv0 += 64) {
    __syncthreads();
#pragma unroll
    for (int it = 0; it < 2; ++it) {
      int idx = (t + it * 256) * 8;
      int kvi = idx >> 6, dh = idx & 63;
      const size_t g = kvbase + (size_t)(kv0 + kvi) * 1024 + dh;
      bf16x8 kvv = *(const bf16x8*)&Kp[g];
      *(bf16x8*)&Klds[kvi][dh] = kvv;
      bf16x8 vv = *(const bf16x8*)&Vp[g];
#pragma unroll
      for (int j = 0; j < 8; ++j) Vlds[dh + j][kvi] = ((unsigned short*)&vv)[j];
    }
    __syncthreads();

    // QK^T: scores[16q x 64kv], D layout row=(l>>4)*4+j, col=l&15
    f32x4 sc[4];
#pragma unroll
    for (int nt = 0; nt < 4; ++nt) {
      f32x4 a = {0.f, 0.f, 0.f, 0.f};
      a = __builtin_amdgcn_mfma_f32_16x16x32_bf16(qf0, *(const bf16x8*)&Klds[nt * 16 + lr][lg], a, 0, 0, 0);
      a = __builtin_amdgcn_mfma_f32_16x16x32_bf16(qf1, *(const bf16x8*)&Klds[nt * 16 + lr][32 + lg], a, 0, 0, 0);
      sc[nt] = a;
    }
    // row max over 64 kv: per-lane 4 tiles, then butterfly across 16 lanes
    float mt[4], alpha[4], rs[4];
#pragma unroll
    for (int j = 0; j < 4; ++j) {
      float m = fmaxf(fmaxf(sc[0][j], sc[1][j]), fmaxf(sc[2][j], sc[3][j]));
      m = fmaxf(m, __shfl_xor(m, 1, 64));
      m = fmaxf(m, __shfl_xor(m, 2, 64));
      m = fmaxf(m, __shfl_xor(m, 4, 64));
      m = fmaxf(m, __shfl_xor(m, 8, 64));
      mt[j] = m;
    }
#pragma unroll
    for (int j = 0; j < 4; ++j) {
      float mnew = fmaxf(m_run[j], mt[j]);
      alpha[j] = exp2f((m_run[j] - mnew) * c);
      m_run[j] = mnew;
      rs[j] = 0.f;
    }
#pragma unroll
    for (int nt = 0; nt < 4; ++nt)
#pragma unroll
      for (int j = 0; j < 4; ++j) {
        float p = exp2f((sc[nt][j] - m_run[j]) * c);
        rs[j] += p;
        Plds[w][lg4 + j][nt * 16 + lr] = f2bf(p);
      }
#pragma unroll
    for (int j = 0; j < 4; ++j) {
      float s = rs[j];
      s += __shfl_xor(s, 1, 64); s += __shfl_xor(s, 2, 64);
      s += __shfl_xor(s, 4, 64); s += __shfl_xor(s, 8, 64);
      l_run[j] = l_run[j] * alpha[j] + s;
    }
#pragma unroll
    for (int nt2 = 0; nt2 < 4; ++nt2)
#pragma unroll
      for (int j = 0; j < 4; ++j) oacc[nt2][j] *= alpha[j];

    bf16x8 pa0 = *(const bf16x8*)&Plds[w][lr][lg];
    bf16x8 pa1 = *(const bf16x8*)&Plds[w][lr][32 + lg];
#pragma unroll
    for (int nt2 = 0; nt2 < 4; ++nt2) {
      oacc[nt2] = __builtin_amdgcn_mfma_f32_16x16x32_bf16(pa0, *(const bf16x8*)&Vlds[nt2 * 16 + lr][lg], oacc[nt2], 0, 0, 0);
      oacc[nt2] = __builtin_amdgcn_mfma_f32_16x16x32_bf16(pa1, *(const bf16x8*)&Vlds[nt2 * 16 + lr][32 + lg], oacc[nt2], 0, 0, 0);
    }
  }

  const size_t orow = (size_t)(b * S_ + qt * 64 + w * 16);
#pragma unroll
  for (int nt2 = 0; nt2 < 4; ++nt2)
#pragma unroll
    for (int j = 0; j < 4; ++j) {
      float v = oacc[nt2][j] / l_run[j];
      O[(orow + lg4 + j) * 1024 + h * 64 + nt2 * 16 + lr] = f2bf(v);
    }
}

extern "C" void kernel_launch(void* const* d_in, const int* in_sizes, int n_in,
                              void* d_out, int out_size, void* d_ws, size_t ws_size,
                              hipStream_t stream) {
  const float* query   = (const float*)d_in[0];
  const float* context = (const float*)d_in[1];
  const float* Wq = (const float*)d_in[2];
  const float* Wk = (const float*)d_in[3];
  const float* Wv = (const float*)d_in[4];
  const float* Wo = (const float*)d_in[5];
  const float* bo = (const float*)d_in[6];
  float* out = (float*)d_out;

  const size_t NA = (size_t)B_ * S_ * D_;  // 4194304
  const size_t NW = (size_t)D_ * D_;       // 1048576
  unsigned short* ws  = (unsigned short*)d_ws;
  unsigned short* qb  = ws;
  unsigned short* cb  = qb + NA;
  unsigned short* WqT = cb + NA;
  unsigned short* WkT = WqT + NW;
  unsigned short* WvT = WkT + NW;
  unsigned short* WoT = WvT + NW;
  unsigned short* qp  = WoT + NW;
  unsigned short* kp  = qp + NA;
  unsigned short* vp  = kp + NA;
  unsigned short* ao  = qb;  // qb is dead after projections; reuse for attn out

  to_bf16_kernel<<<(int)(NA / 4 / 256), 256, 0, stream>>>(query, qb, (int)(NA / 4));
  to_bf16_kernel<<<(int)(NA / 4 / 256), 256, 0, stream>>>(context, cb, (int)(NA / 4));
  dim3 tg(32, 32);
  transpose_bf16_kernel<<<tg, 256, 0, stream>>>(Wq, WqT);
  transpose_bf16_kernel<<<tg, 256, 0, stream>>>(Wk, WkT);
  transpose_bf16_kernel<<<tg, 256, 0, stream>>>(Wv, WvT);
  transpose_bf16_kernel<<<tg, 256, 0, stream>>>(Wo, WoT);

  dim3 gg(32, 8);
  gemm_bt<0><<<gg, 256, 0, stream>>>(qb, WqT, nullptr, qp, 4096, 1024, 1024);
  gemm_bt<0><<<gg, 256, 0, stream>>>(cb, WkT, nullptr, kp, 4096, 1024, 1024);
  gemm_bt<0><<<gg, 256, 0, stream>>>(cb, WvT, nullptr, vp, 4096, 1024, 1024);

  attn_kernel<<<dim3(S_ / 64, H_, B_), 256, 0, stream>>>(qp, kp, vp, ao);

  gemm_bt<1><<<gg, 256, 0, stream>>>(ao, WoT, bo, out, 4096, 1024, 1024);
}

// Round 2
// 162.852 us; speedup vs baseline: 1.9225x; 1.9225x over previous
//
#include <hip/hip_runtime.h>
#include <hip/hip_bf16.h>

typedef __attribute__((ext_vector_type(8))) short bf16x8;
typedef __attribute__((ext_vector_type(4))) float f32x4;

#define B_ 2
#define S_ 2048
#define D_ 1024
#define H_ 16

__device__ __forceinline__ unsigned short f2bf(float x) {
  unsigned u = __float_as_uint(x);
  unsigned r = (u + 0x7fffu + ((u >> 16) & 1u)) >> 16;
  return (unsigned short)r;
}

__device__ __forceinline__ unsigned cvt_pk_bf16(float lo, float hi) {
  unsigned r;
  asm("v_cvt_pk_bf16_f32 %0, %1, %2" : "=v"(r) : "v"(lo), "v"(hi));
  return r;
}

__device__ __forceinline__ void gload_lds16(const void* g, void* l) {
  __builtin_amdgcn_global_load_lds((const __attribute__((address_space(1))) void*)g,
                                   (__attribute__((address_space(3))) void*)l, 16, 0, 0);
}

// ---------------- fp32 -> bf16 convert (both activations in one launch) ----------------
__global__ __launch_bounds__(256) void to_bf16_2(const float* __restrict__ q,
                                                 const float* __restrict__ ctx,
                                                 unsigned short* __restrict__ qb,
                                                 unsigned short* __restrict__ cb) {
  int i = blockIdx.x * 256 + threadIdx.x;
  const float* s = blockIdx.y ? ctx : q;
  unsigned short* d = blockIdx.y ? cb : qb;
  float4 v = ((const float4*)s)[i];
  ushort4 o;
  o.x = f2bf(v.x); o.y = f2bf(v.y); o.z = f2bf(v.z); o.w = f2bf(v.w);
  ((ushort4*)d)[i] = o;
}

// ---------------- fp32 [K][N] -> bf16 [N][K] transpose (all 4 weights, z-select) ----------------
__global__ __launch_bounds__(256) void transpose4(const float* __restrict__ Wq, const float* __restrict__ Wk,
                                                  const float* __restrict__ Wv, const float* __restrict__ Wo,
                                                  unsigned short* __restrict__ WqT, unsigned short* __restrict__ WkT,
                                                  unsigned short* __restrict__ WvT, unsigned short* __restrict__ WoT) {
  __shared__ float tile[32][33];
  const float* W; unsigned short* WT;
  int z = blockIdx.z;
  if (z == 0)      { W = Wq; WT = WqT; }
  else if (z == 1) { W = Wk; WT = WkT; }
  else if (z == 2) { W = Wv; WT = WvT; }
  else             { W = Wo; WT = WoT; }
  int r0 = blockIdx.y * 32, c0 = blockIdx.x * 32;
  int t = threadIdx.x;
  int lr = t >> 3, lc = (t & 7) * 4;
  float4 v = *(const float4*)&W[(size_t)(r0 + lr) * 1024 + c0 + lc];
  tile[lr][lc + 0] = v.x; tile[lr][lc + 1] = v.y; tile[lr][lc + 2] = v.z; tile[lr][lc + 3] = v.w;
  __syncthreads();
  ushort4 o;
  o.x = f2bf(tile[lc + 0][lr]);
  o.y = f2bf(tile[lc + 1][lr]);
  o.z = f2bf(tile[lc + 2][lr]);
  o.w = f2bf(tile[lc + 3][lr]);
  *(ushort4*)&WT[(size_t)(c0 + lr) * 1024 + r0 + lc] = o;
}

// ---------------- GEMM core: C[M,N] = A[M,K] * BT[N,K]^T, 128x128 tile, BK=32 ----------------
__device__ __forceinline__ void gemm_core(const unsigned short* __restrict__ A,
                                          const unsigned short* __restrict__ BT,
                                          int m0, int n0, int K,
                                          unsigned short* As, unsigned short* Bs,
                                          f32x4 (&acc)[4][4]) {
  const int t = threadIdx.x, w = t >> 6, l = t & 63;
  const int lr = l & 15, lg = (l >> 4) * 8;
  const int wm = (w >> 1) * 64, wn = (w & 1) * 64;
  for (int k0 = 0; k0 < K; k0 += 32) {
    __syncthreads();
#pragma unroll
    for (int it = 0; it < 2; ++it) {
      int o = t * 16 + it * 4096;           // byte offset in 8KB tile
      int row = o >> 6, ce = (o & 63) >> 1; // row, col-elem
      gload_lds16(A + (size_t)(m0 + row) * K + k0 + ce, (char*)As + it * 4096 + w * 1024);
      gload_lds16(BT + (size_t)(n0 + row) * K + k0 + ce, (char*)Bs + it * 4096 + w * 1024);
    }
    __syncthreads();
    bf16x8 af[4], bfr[4];
#pragma unroll
    for (int mi = 0; mi < 4; ++mi) af[mi] = *(const bf16x8*)&As[(wm + mi * 16 + lr) * 32 + lg];
#pragma unroll
    for (int ni = 0; ni < 4; ++ni) bfr[ni] = *(const bf16x8*)&Bs[(wn + ni * 16 + lr) * 32 + lg];
#pragma unroll
    for (int mi = 0; mi < 4; ++mi)
#pragma unroll
      for (int ni = 0; ni < 4; ++ni)
        acc[mi][ni] = __builtin_amdgcn_mfma_f32_16x16x32_bf16(af[mi], bfr[ni], acc[mi][ni], 0, 0, 0);
  }
}

// ---------------- fused QKV projection (768 blocks, 3/CU) ----------------
// z=0: qp = qb*WqT^T [4096x1024]; z=1: kp = cb*WkT^T; z=2: vt = WvT*cb^T = V^T [1024x4096]
__global__ __launch_bounds__(256) void gemm_qkv(const unsigned short* __restrict__ qb,
                                                const unsigned short* __restrict__ cb,
                                                const unsigned short* __restrict__ WqT,
                                                const unsigned short* __restrict__ WkT,
                                                const unsigned short* __restrict__ WvT,
                                                unsigned short* __restrict__ qp,
                                                unsigned short* __restrict__ kp,
                                                unsigned short* __restrict__ vt) {
  __shared__ unsigned short As[128 * 32];
  __shared__ unsigned short Bs[128 * 32];
  int bid = blockIdx.x, z = bid >> 8, r = bid & 255;
  const unsigned short *A, *BT; unsigned short* C; int N, bx, by;
  if (z == 0)      { A = qb;  BT = WqT; C = qp; N = 1024; bx = r & 31; by = r >> 5; }
  else if (z == 1) { A = cb;  BT = WkT; C = kp; N = 1024; bx = r & 31; by = r >> 5; }
  else             { A = WvT; BT = cb;  C = vt; N = 4096; bx = r & 7;  by = r >> 3; }
  f32x4 acc[4][4];
#pragma unroll
  for (int mi = 0; mi < 4; ++mi)
#pragma unroll
    for (int ni = 0; ni < 4; ++ni) acc[mi][ni] = {0.f, 0.f, 0.f, 0.f};
  gemm_core(A, BT, bx * 128, by * 128, 1024, As, Bs, acc);
  const int t = threadIdx.x, w = t >> 6, l = t & 63;
  const int lr = l & 15, lg4 = (l >> 4) * 4;
  const int wm = (w >> 1) * 64, wn = (w & 1) * 64;
#pragma unroll
  for (int mi = 0; mi < 4; ++mi)
#pragma unroll
    for (int ni = 0; ni < 4; ++ni)
#pragma unroll
      for (int j = 0; j < 4; ++j)
        C[(size_t)(bx * 128 + wm + mi * 16 + lg4 + j) * N + by * 128 + wn + ni * 16 + lr] =
            f2bf(acc[mi][ni][j]);
}

// ---------------- final projection: out = ao*WoT^T + bo (fp32) ----------------
__global__ __launch_bounds__(256) void gemm_out(const unsigned short* __restrict__ A,
                                                const unsigned short* __restrict__ BT,
                                                const float* __restrict__ bias,
                                                float* __restrict__ C) {
  __shared__ unsigned short As[128 * 32];
  __shared__ unsigned short Bs[128 * 32];
  int bx = blockIdx.x, by = blockIdx.y;
  f32x4 acc[4][4];
#pragma unroll
  for (int mi = 0; mi < 4; ++mi)
#pragma unroll
    for (int ni = 0; ni < 4; ++ni) acc[mi][ni] = {0.f, 0.f, 0.f, 0.f};
  gemm_core(A, BT, bx * 128, by * 128, 1024, As, Bs, acc);
  const int t = threadIdx.x, w = t >> 6, l = t & 63;
  const int lr = l & 15, lg4 = (l >> 4) * 4;
  const int wm = (w >> 1) * 64, wn = (w & 1) * 64;
#pragma unroll
  for (int mi = 0; mi < 4; ++mi)
#pragma unroll
    for (int ni = 0; ni < 4; ++ni) {
      int col = by * 128 + wn + ni * 16 + lr;
      float bv = bias[col];
#pragma unroll
      for (int j = 0; j < 4; ++j)
        C[(size_t)(bx * 128 + wm + mi * 16 + lg4 + j) * 1024 + col] = acc[mi][ni][j] + bv;
    }
}

// ---------------- flash attention, swapped-QK^T, swizzled LDS, dbuf staging ----------------
// 1D grid 1024 (XCD-grouped remap); block 256 = 4 waves; wave w: 16 q-rows.
__global__ __launch_bounds__(256) void attn_kernel(const unsigned short* __restrict__ Q,
                                                   const unsigned short* __restrict__ Kp,
                                                   const unsigned short* __restrict__ Vt,
                                                   unsigned short* __restrict__ O) {
  __shared__ char lds[32768];  // [2 bufs][K 8KB | Vt 8KB]
  const int t = threadIdx.x, w = t >> 6, l = t & 63;
  const int lr = l & 15, g = l >> 4;
  const int bid = blockIdx.x;
  const int nf = (bid & 7) * 128 + (bid >> 3);  // XCD-grouped: one (b,h) per XCD chunk
  const int qt = nf & 31, h = (nf >> 5) & 15, b = nf >> 9;
  const float c = 0.125f * 1.44269504089f;  // 1/sqrt(64) * log2(e)

  // Q fragment (B-operand: col=q=lr, k=dh)
  const size_t qrow = ((size_t)(b * S_ + qt * 64 + w * 16 + lr)) * 1024 + h * 64;
  const bf16x8 qf0 = *(const bf16x8*)&Q[qrow + g * 8];
  const bf16x8 qf1 = *(const bf16x8*)&Q[qrow + 32 + g * 8];

  const size_t kbase = (size_t)b * S_ * 1024 + h * 64;              // K: [s][1024]
  const size_t vtb = (size_t)(h * 64) * 4096 + (size_t)b * 2048;    // Vt: [1024][4096]

  f32x4 oacc[4];
#pragma unroll
  for (int i = 0; i < 4; ++i) oacc[i] = {0.f, 0.f, 0.f, 0.f};
  float m_run = -1e30f, l_run = 0.f;

  // stage K-tile [64 kv][64 dh] and Vt-tile [64 dh][64 kv], XOR-swizzled via
  // pre-swizzled GLOBAL source column + linear global_load_lds dest (m173).
#define STAGE(bsel, kv0) do {                                                          \
    char* kdst = lds + (bsel) * 16384;                                                 \
    char* vdst = kdst + 8192;                                                          \
    _Pragma("unroll")                                                                  \
    for (int it_ = 0; it_ < 2; ++it_) {                                                \
      const int off_ = it_ * 4096 + w * 1024 + l * 16;                                 \
      const int row_ = off_ >> 7, cb_ = off_ & 127;                                    \
      const int sc_ = (cb_ ^ ((row_ & 7) << 4)) >> 1;                                  \
      gload_lds16(Kp + kbase + (size_t)((kv0) + row_) * 1024 + sc_,                    \
                  kdst + it_ * 4096 + w * 1024);                                       \
      gload_lds16(Vt + vtb + (size_t)row_ * 4096 + (kv0) + sc_,                        \
                  vdst + it_ * 4096 + w * 1024);                                       \
    }                                                                                  \
  } while (0)

  STAGE(0, 0);
  __syncthreads();
  int cur = 0;
  const int sw = (lr & 7) << 4;

  for (int tile = 0; tile < 32; ++tile) {
    if (tile < 31) STAGE(cur ^ 1, (tile + 1) * 64);
    const char* kb = lds + cur * 16384;
    const char* vb = kb + 8192;

    // S^T = K * Q^T: D[row=kv][col=q]; sc[nt][j] = S[kv=nt*16+g*4+j][q=lr]
    f32x4 sc[4];
#pragma unroll
    for (int nt = 0; nt < 4; ++nt) {
      const int row = nt * 16 + lr;
      bf16x8 k0 = *(const bf16x8*)(kb + row * 128 + ((g * 16) ^ sw));
      bf16x8 k1 = *(const bf16x8*)(kb + row * 128 + ((64 + g * 16) ^ sw));
      f32x4 a = {0.f, 0.f, 0.f, 0.f};
      a = __builtin_amdgcn_mfma_f32_16x16x32_bf16(k0, qf0, a, 0, 0, 0);
      a = __builtin_amdgcn_mfma_f32_16x16x32_bf16(k1, qf1, a, 0, 0, 0);
      sc[nt] = a;
    }

    // online softmax for q=lr: local 16-max, then across groups (xor 16, 32)
    float mt = sc[0][0];
#pragma unroll
    for (int nt = 0; nt < 4; ++nt)
#pragma unroll
      for (int j = 0; j < 4; ++j) mt = fmaxf(mt, sc[nt][j]);
    mt = fmaxf(mt, __shfl_xor(mt, 16, 64));
    mt = fmaxf(mt, __shfl_xor(mt, 32, 64));
    float mnew = fmaxf(m_run, mt);
    float alpha = exp2f((m_run - mnew) * c);
    m_run = mnew;

    float p[4][4];
    float rs = 0.f;
#pragma unroll
    for (int nt = 0; nt < 4; ++nt)
#pragma unroll
      for (int j = 0; j < 4; ++j) {
        p[nt][j] = exp2f((sc[nt][j] - mnew) * c);
        rs += p[nt][j];
      }
    rs += __shfl_xor(rs, 16, 64);
    rs += __shfl_xor(rs, 32, 64);
    l_run = l_run * alpha + rs;

    // pack P to bf16 pairs: pk[nt][wd] = {P[.][nt*16+g*4+2wd], P[.][+1]}
    unsigned pk[4][2];
#pragma unroll
    for (int nt = 0; nt < 4; ++nt) {
      pk[nt][0] = cvt_pk_bf16(p[nt][0], p[nt][1]);
      pk[nt][1] = cvt_pk_bf16(p[nt][2], p[nt][3]);
    }

    // rescale O accumulator: acc row q = g*4+j needs alpha from lane q
    float a4[4];
#pragma unroll
    for (int j = 0; j < 4; ++j) a4[j] = __shfl(alpha, g * 4 + j, 64);
#pragma unroll
    for (int nt2 = 0; nt2 < 4; ++nt2)
#pragma unroll
      for (int j = 0; j < 4; ++j) oacc[nt2][j] *= a4[j];

    // PV: A-frag P[q=lr][kv=kt*32+g*8+e] gathered from lanes (lr, g_s)
    const int src_a = lr + 16 * ((2 * g) & 3);
    const int src_b = lr + 16 * ((2 * g + 1) & 3);
    const bool hi = g >= 2;
#pragma unroll
    for (int kt = 0; kt < 2; ++kt) {
      unsigned la0 = (unsigned)__shfl((int)pk[2 * kt][0], src_a, 64);
      unsigned la1 = (unsigned)__shfl((int)pk[2 * kt][1], src_a, 64);
      unsigned ha0 = (unsigned)__shfl((int)pk[2 * kt + 1][0], src_a, 64);
      unsigned ha1 = (unsigned)__shfl((int)pk[2 * kt + 1][1], src_a, 64);
      unsigned lb0 = (unsigned)__shfl((int)pk[2 * kt][0], src_b, 64);
      unsigned lb1 = (unsigned)__shfl((int)pk[2 * kt][1], src_b, 64);
      unsigned hb0 = (unsigned)__shfl((int)pk[2 * kt + 1][0], src_b, 64);
      unsigned hb1 = (unsigned)__shfl((int)pk[2 * kt + 1][1], src_b, 64);
      union { unsigned u[4]; bf16x8 v; } pa;
      pa.u[0] = hi ? ha0 : la0;
      pa.u[1] = hi ? ha1 : la1;
      pa.u[2] = hi ? hb0 : lb0;
      pa.u[3] = hi ? hb1 : lb1;
#pragma unroll
      for (int nt2 = 0; nt2 < 4; ++nt2) {
        const int r2 = nt2 * 16 + lr;
        bf16x8 vf = *(const bf16x8*)(vb + r2 * 128 + ((kt * 64 + g * 16) ^ sw));
        oacc[nt2] = __builtin_amdgcn_mfma_f32_16x16x32_bf16(pa.v, vf, oacc[nt2], 0, 0, 0);
      }
    }
    __syncthreads();  // drains vmcnt for next-tile stage + buffer-reuse barrier
    cur ^= 1;
  }

  float lr4[4];
#pragma unroll
  for (int j = 0; j < 4; ++j) lr4[j] = 1.f / __shfl(l_run, g * 4 + j, 64);
  const size_t ob = ((size_t)(b * S_ + qt * 64 + w * 16)) * 1024 + h * 64;
#pragma unroll
  for (int nt2 = 0; nt2 < 4; ++nt2)
#pragma unroll
    for (int j = 0; j < 4; ++j)
      O[ob + (size_t)(g * 4 + j) * 1024 + nt2 * 16 + lr] = f2bf(oacc[nt2][j] * lr4[j]);
#undef STAGE
}

extern "C" void kernel_launch(void* const* d_in, const int* in_sizes, int n_in,
                              void* d_out, int out_size, void* d_ws, size_t ws_size,
                              hipStream_t stream) {
  const float* query   = (const float*)d_in[0];
  const float* context = (const float*)d_in[1];
  const float* Wq = (const float*)d_in[2];
  const float* Wk = (const float*)d_in[3];
  const float* Wv = (const float*)d_in[4];
  const float* Wo = (const float*)d_in[5];
  const float* bo = (const float*)d_in[6];
  float* out = (float*)d_out;

  const size_t NA = (size_t)B_ * S_ * D_;  // 4 Mi elems
  const size_t NW = (size_t)D_ * D_;       // 1 Mi elems
  unsigned short* ws  = (unsigned short*)d_ws;
  unsigned short* qb  = ws;
  unsigned short* cb  = qb + NA;
  unsigned short* WqT = cb + NA;
  unsigned short* WkT = WqT + NW;
  unsigned short* WvT = WkT + NW;
  unsigned short* WoT = WvT + NW;
  unsigned short* qp  = WoT + NW;
  unsigned short* kp  = qp + NA;
  unsigned short* vt  = kp + NA;           // V^T [1024][4096]
  unsigned short* ao  = qb;                // reuse qb after projections

  to_bf16_2<<<dim3((unsigned)(NA / 4 / 256), 2), 256, 0, stream>>>(query, context, qb, cb);
  transpose4<<<dim3(32, 32, 4), 256, 0, stream>>>(Wq, Wk, Wv, Wo, WqT, WkT, WvT, WoT);
  gemm_qkv<<<768, 256, 0, stream>>>(qb, cb, WqT, WkT, WvT, qp, kp, vt);
  attn_kernel<<<1024, 256, 0, stream>>>(qp, kp, vt, ao);
  gemm_out<<<dim3(32, 8), 256, 0, stream>>>(ao, WoT, bo, out);
}

// Round 3
// 153.496 us; speedup vs baseline: 2.0397x; 1.0610x over previous
//
#include <hip/hip_runtime.h>
#include <hip/hip_bf16.h>

typedef __attribute__((ext_vector_type(8))) short bf16x8;
typedef __attribute__((ext_vector_type(4))) float f32x4;
typedef __attribute__((ext_vector_type(16))) float f32x16;

#define B_ 2
#define S_ 2048
#define D_ 1024
#define H_ 16

__device__ __forceinline__ unsigned short f2bf(float x) {
  unsigned u = __float_as_uint(x);
  unsigned r = (u + 0x7fffu + ((u >> 16) & 1u)) >> 16;
  return (unsigned short)r;
}

__device__ __forceinline__ unsigned cvt_pk_bf16(float lo, float hi) {
  unsigned r;
  asm("v_cvt_pk_bf16_f32 %0, %1, %2" : "=v"(r) : "v"(lo), "v"(hi));
  return r;
}

__device__ __forceinline__ void gload_lds16(const void* g, void* l) {
  __builtin_amdgcn_global_load_lds((const __attribute__((address_space(1))) void*)g,
                                   (__attribute__((address_space(3))) void*)l, 16, 0, 0);
}

// ---------------- prep: bf16 convert (q, ctx) + 4 weight transposes, one launch ----------------
__global__ __launch_bounds__(256) void prep_kernel(const float* __restrict__ query,
                                                   const float* __restrict__ ctx,
                                                   const float* __restrict__ Wq, const float* __restrict__ Wk,
                                                   const float* __restrict__ Wv, const float* __restrict__ Wo,
                                                   unsigned short* __restrict__ qb, unsigned short* __restrict__ cb,
                                                   unsigned short* __restrict__ WqT, unsigned short* __restrict__ WkT,
                                                   unsigned short* __restrict__ WvT, unsigned short* __restrict__ WoT) {
  __shared__ float tile[32][33];
  int bid = blockIdx.x;
  if (bid < 8192) {
    const float* s = bid < 4096 ? query : ctx;
    unsigned short* d = bid < 4096 ? qb : cb;
    int i = (bid & 4095) * 256 + threadIdx.x;
    float4 v = ((const float4*)s)[i];
    ushort4 o;
    o.x = f2bf(v.x); o.y = f2bf(v.y); o.z = f2bf(v.z); o.w = f2bf(v.w);
    ((ushort4*)d)[i] = o;
    return;
  }
  int tid = bid - 8192;              // 4096 transpose blocks
  int z = tid >> 10, r = tid & 1023;
  const float* W; unsigned short* WT;
  if (z == 0)      { W = Wq; WT = WqT; }
  else if (z == 1) { W = Wk; WT = WkT; }
  else if (z == 2) { W = Wv; WT = WvT; }
  else             { W = Wo; WT = WoT; }
  int r0 = (r >> 5) * 32, c0 = (r & 31) * 32;
  int t = threadIdx.x;
  int lr = t >> 3, lc = (t & 7) * 4;
  float4 v = *(const float4*)&W[(size_t)(r0 + lr) * 1024 + c0 + lc];
  tile[lr][lc + 0] = v.x; tile[lr][lc + 1] = v.y; tile[lr][lc + 2] = v.z; tile[lr][lc + 3] = v.w;
  __syncthreads();
  ushort4 o;
  o.x = f2bf(tile[lc + 0][lr]);
  o.y = f2bf(tile[lc + 1][lr]);
  o.z = f2bf(tile[lc + 2][lr]);
  o.w = f2bf(tile[lc + 3][lr]);
  *(ushort4*)&WT[(size_t)(c0 + lr) * 1024 + r0 + lc] = o;
}

// ---------------- GEMM core (double-buffered, single barrier/tile): C = A[M,K]*BT[N,K]^T ----------------
__device__ __forceinline__ void gemm_core(const unsigned short* __restrict__ A,
                                          const unsigned short* __restrict__ BT,
                                          int m0, int n0, int K,
                                          unsigned short* As, unsigned short* Bs,
                                          f32x4 (&acc)[4][4]) {
  const int t = threadIdx.x, w = t >> 6, l = t & 63;
  const int lr = l & 15, lg = (l >> 4) * 8;
  const int wm = (w >> 1) * 64, wn = (w & 1) * 64;

#define GSTAGE(buf, k0) do {                                                               \
    _Pragma("unroll")                                                                      \
    for (int it_ = 0; it_ < 2; ++it_) {                                                    \
      int o_ = t * 16 + it_ * 4096;                                                        \
      int row_ = o_ >> 6, ce_ = (o_ & 63) >> 1;                                            \
      gload_lds16(A + (size_t)(m0 + row_) * K + (k0) + ce_,                                \
                  (char*)As + (buf) * 8192 + it_ * 4096 + w * 1024);                       \
      gload_lds16(BT + (size_t)(n0 + row_) * K + (k0) + ce_,                               \
                  (char*)Bs + (buf) * 8192 + it_ * 4096 + w * 1024);                       \
    }                                                                                      \
  } while (0)

  GSTAGE(0, 0);
  __syncthreads();
  int cur = 0;
  const int NT = K >> 5;
  for (int kt = 0; kt < NT; ++kt) {
    if (kt < NT - 1) GSTAGE(cur ^ 1, (kt + 1) * 32);
    bf16x8 af[4], bfr[4];
#pragma unroll
    for (int mi = 0; mi < 4; ++mi) af[mi] = *(const bf16x8*)&As[cur * 4096 + (wm + mi * 16 + lr) * 32 + lg];
#pragma unroll
    for (int ni = 0; ni < 4; ++ni) bfr[ni] = *(const bf16x8*)&Bs[cur * 4096 + (wn + ni * 16 + lr) * 32 + lg];
#pragma unroll
    for (int mi = 0; mi < 4; ++mi)
#pragma unroll
      for (int ni = 0; ni < 4; ++ni)
        acc[mi][ni] = __builtin_amdgcn_mfma_f32_16x16x32_bf16(af[mi], bfr[ni], acc[mi][ni], 0, 0, 0);
    __syncthreads();
    cur ^= 1;
  }
#undef GSTAGE
}

// ---------------- fused QKV projection (768 blocks) ----------------
__global__ __launch_bounds__(256) void gemm_qkv(const unsigned short* __restrict__ qb,
                                                const unsigned short* __restrict__ cb,
                                                const unsigned short* __restrict__ WqT,
                                                const unsigned short* __restrict__ WkT,
                                                const unsigned short* __restrict__ WvT,
                                                unsigned short* __restrict__ qp,
                                                unsigned short* __restrict__ kp,
                                                unsigned short* __restrict__ vt) {
  __shared__ unsigned short As[2 * 4096];
  __shared__ unsigned short Bs[2 * 4096];
  int wg = (blockIdx.x & 7) * 96 + (blockIdx.x >> 3);  // XCD swizzle (768 % 8 == 0)
  int z = wg >> 8, r = wg & 255;
  const unsigned short *A, *BT; unsigned short* C; int N, bx, by;
  if (z == 0)      { A = qb;  BT = WqT; C = qp; N = 1024; bx = r & 31; by = r >> 5; }
  else if (z == 1) { A = cb;  BT = WkT; C = kp; N = 1024; bx = r & 31; by = r >> 5; }
  else             { A = WvT; BT = cb;  C = vt; N = 4096; bx = r & 7;  by = r >> 3; }
  f32x4 acc[4][4];
#pragma unroll
  for (int mi = 0; mi < 4; ++mi)
#pragma unroll
    for (int ni = 0; ni < 4; ++ni) acc[mi][ni] = {0.f, 0.f, 0.f, 0.f};
  gemm_core(A, BT, bx * 128, by * 128, 1024, As, Bs, acc);
  const int t = threadIdx.x, w = t >> 6, l = t & 63;
  const int lr = l & 15, lg4 = (l >> 4) * 4;
  const int wm = (w >> 1) * 64, wn = (w & 1) * 64;
#pragma unroll
  for (int mi = 0; mi < 4; ++mi)
#pragma unroll
    for (int ni = 0; ni < 4; ++ni)
#pragma unroll
      for (int j = 0; j < 4; ++j)
        C[(size_t)(bx * 128 + wm + mi * 16 + lg4 + j) * N + by * 128 + wn + ni * 16 + lr] =
            f2bf(acc[mi][ni][j]);
}

// ---------------- final projection: out = ao*WoT^T + bo (fp32) ----------------
__global__ __launch_bounds__(256) void gemm_out(const unsigned short* __restrict__ A,
                                                const unsigned short* __restrict__ BT,
                                                const float* __restrict__ bias,
                                                float* __restrict__ C) {
  __shared__ unsigned short As[2 * 4096];
  __shared__ unsigned short Bs[2 * 4096];
  int wg = (blockIdx.x & 7) * 32 + (blockIdx.x >> 3);  // 256 blocks
  int bx = wg & 31, by = wg >> 5;
  f32x4 acc[4][4];
#pragma unroll
  for (int mi = 0; mi < 4; ++mi)
#pragma unroll
    for (int ni = 0; ni < 4; ++ni) acc[mi][ni] = {0.f, 0.f, 0.f, 0.f};
  gemm_core(A, BT, bx * 128, by * 128, 1024, As, Bs, acc);
  const int t = threadIdx.x, w = t >> 6, l = t & 63;
  const int lr = l & 15, lg4 = (l >> 4) * 4;
  const int wm = (w >> 1) * 64, wn = (w & 1) * 64;
#pragma unroll
  for (int mi = 0; mi < 4; ++mi)
#pragma unroll
    for (int ni = 0; ni < 4; ++ni) {
      int col = by * 128 + wn + ni * 16 + lr;
      float bv = bias[col];
#pragma unroll
      for (int j = 0; j < 4; ++j)
        C[(size_t)(bx * 128 + wm + mi * 16 + lg4 + j) * 1024 + col] = acc[mi][ni][j] + bv;
    }
}

// ---------------- flash attention, 32x32x16 swapped structure ----------------
// grid 512 (XCD-grouped); block 256 = 4 waves; wave w owns q-rows [qt*128+w*32, +32).
// Lane l: q = l&31 (col of both S^T and O^T accumulators) -> softmax is lane-local
// except one shfl_xor(32) per reduction.
__global__ __launch_bounds__(256) void attn_kernel(const unsigned short* __restrict__ Q,
                                                   const unsigned short* __restrict__ Kp,
                                                   const unsigned short* __restrict__ Vt,
                                                   unsigned short* __restrict__ O) {
  __shared__ char lds[32768];  // [2 bufs][K 8KB | Vt 8KB]
  const int t = threadIdx.x, w = t >> 6, l = t & 63;
  const int l31 = l & 31, hi = l >> 5;
  const int nf = (blockIdx.x & 7) * 64 + (blockIdx.x >> 3);
  const int qt = nf & 15, h = (nf >> 4) & 15, b = nf >> 8;
  const float cs = 0.125f * 1.44269504089f;  // 1/sqrt(64) * log2(e)

  const int q = qt * 128 + w * 32 + l31;
  const size_t qbase = ((size_t)(b * S_ + q)) * 1024 + h * 64;
  bf16x8 qf[4];  // B-frag: Q[q][k = c*16 + hi*8 + e]
#pragma unroll
  for (int c = 0; c < 4; ++c) qf[c] = *(const bf16x8*)&Q[qbase + c * 16 + hi * 8];

  const size_t kbase = (size_t)b * S_ * 1024 + h * 64;            // K: [s][1024]
  const size_t vtb = (size_t)(h * 64) * 4096 + (size_t)b * 2048;  // Vt: [1024][4096]

  f32x16 oacc[2];  // O^T[dh = dblk*32 + rowpat][q = l31]
#pragma unroll
  for (int d = 0; d < 2; ++d)
#pragma unroll
    for (int r = 0; r < 16; ++r) oacc[d][r] = 0.f;
  float m_run = -1e30f, l_run = 0.f;

#define STAGE(bsel, kv0) do {                                                          \
    char* kdst = lds + (bsel) * 16384;                                                 \
    char* vdst = kdst + 8192;                                                          \
    _Pragma("unroll")                                                                  \
    for (int it_ = 0; it_ < 2; ++it_) {                                                \
      const int off_ = it_ * 4096 + w * 1024 + l * 16;                                 \
      const int row_ = off_ >> 7, cb_ = off_ & 127;                                    \
      const int sc_ = (cb_ ^ ((row_ & 7) << 4)) >> 1;                                  \
      gload_lds16(Kp + kbase + (size_t)((kv0) + row_) * 1024 + sc_,                    \
                  kdst + it_ * 4096 + w * 1024);                                       \
      gload_lds16(Vt + vtb + (size_t)row_ * 4096 + (kv0) + sc_,                        \
                  vdst + it_ * 4096 + w * 1024);                                       \
    }                                                                                  \
  } while (0)

  STAGE(0, 0);
  __syncthreads();
  int cur = 0;
  const int sw = (l & 7) << 4;

  for (int tile = 0; tile < 32; ++tile) {
    if (tile < 31) STAGE(cur ^ 1, (tile + 1) * 64);
    const char* kb = lds + cur * 16384;
    const char* vb = kb + 8192;

    // S^T[kv][q]: A = K[kv row][dh k-slice], B = Q
    f32x16 sacc[2];
#pragma unroll
    for (int kvb = 0; kvb < 2; ++kvb) {
#pragma unroll
      for (int r = 0; r < 16; ++r) sacc[kvb][r] = 0.f;
      const int row = kvb * 32 + l31;
#pragma unroll
      for (int c = 0; c < 4; ++c) {
        bf16x8 kf = *(const bf16x8*)(kb + row * 128 + ((c * 32 + hi * 16) ^ sw));
        sacc[kvb] = __builtin_amdgcn_mfma_f32_32x32x16_bf16(kf, qf[c], sacc[kvb], 0, 0, 0);
      }
    }

    // online softmax for q=l31 (lane pair l, l^32 holds complementary kv rows)
    float mt = sacc[0][0];
#pragma unroll
    for (int kvb = 0; kvb < 2; ++kvb)
#pragma unroll
      for (int r = 0; r < 16; ++r) mt = fmaxf(mt, sacc[kvb][r]);
    mt = fmaxf(mt, __shfl_xor(mt, 32, 64));
    float mnew = fmaxf(m_run, mt);
    float al = exp2f((m_run - mnew) * cs);
    m_run = mnew;
    const float mc = mnew * cs;
    float rs = 0.f;
#pragma unroll
    for (int kvb = 0; kvb < 2; ++kvb)
#pragma unroll
      for (int r = 0; r < 16; ++r) {
        float p = exp2f(sacc[kvb][r] * cs - mc);
        sacc[kvb][r] = p;
        rs += p;
      }
    rs += __shfl_xor(rs, 32, 64);
    l_run = l_run * al + rs;
#pragma unroll
    for (int d = 0; d < 2; ++d)
#pragma unroll
      for (int r = 0; r < 16; ++r) oacc[d][r] *= al;

    // PV: per 16-kv chunk c, build B-frag P[k=hi*8+e][q] via 2 shfl_xor,
    // A = V^T[dh][kv] from LDS.  O^T += V^T * P
#pragma unroll
    for (int c = 0; c < 4; ++c) {
      const int sb = c >> 1, r0 = (c & 1) * 8;
      unsigned wA = cvt_pk_bf16(sacc[sb][r0 + 0], sacc[sb][r0 + 1]);  // in-chunk rows (0,1)+4hi
      unsigned wB = cvt_pk_bf16(sacc[sb][r0 + 2], sacc[sb][r0 + 3]);  // (2,3)+4hi
      unsigned wC = cvt_pk_bf16(sacc[sb][r0 + 4], sacc[sb][r0 + 5]);  // (8,9)+4hi
      unsigned wD = cvt_pk_bf16(sacc[sb][r0 + 6], sacc[sb][r0 + 7]);  // (10,11)+4hi
      unsigned s0 = hi ? wA : wC;
      unsigned s1 = hi ? wB : wD;
      unsigned x0 = (unsigned)__shfl_xor((int)s0, 32, 64);
      unsigned x1 = (unsigned)__shfl_xor((int)s1, 32, 64);
      union { unsigned u[4]; bf16x8 v; } pf;
      pf.u[0] = hi ? x0 : wA;
      pf.u[1] = hi ? x1 : wB;
      pf.u[2] = hi ? wC : x0;
      pf.u[3] = hi ? wD : x1;
#pragma unroll
      for (int d = 0; d < 2; ++d) {
        const int vrow = d * 32 + l31;
        bf16x8 vf = *(const bf16x8*)(vb + vrow * 128 + ((c * 32 + hi * 16) ^ sw));
        oacc[d] = __builtin_amdgcn_mfma_f32_32x32x16_bf16(vf, pf.v, oacc[d], 0, 0, 0);
      }
    }
    __syncthreads();
    cur ^= 1;
  }

  // epilogue: lane writes its own q-row; dh = 32d + 8rg + 4hi + (0..3)
  const float inv = 1.f / l_run;
#pragma unroll
  for (int d = 0; d < 2; ++d)
#pragma unroll
    for (int rg = 0; rg < 4; ++rg) {
      ushort4 o4;
      o4.x = f2bf(oacc[d][rg * 4 + 0] * inv);
      o4.y = f2bf(oacc[d][rg * 4 + 1] * inv);
      o4.z = f2bf(oacc[d][rg * 4 + 2] * inv);
      o4.w = f2bf(oacc[d][rg * 4 + 3] * inv);
      *(ushort4*)&O[qbase + d * 32 + rg * 8 + hi * 4] = o4;
    }
#undef STAGE
}

extern "C" void kernel_launch(void* const* d_in, const int* in_sizes, int n_in,
                              void* d_out, int out_size, void* d_ws, size_t ws_size,
                              hipStream_t stream) {
  const float* query   = (const float*)d_in[0];
  const float* context = (const float*)d_in[1];
  const float* Wq = (const float*)d_in[2];
  const float* Wk = (const float*)d_in[3];
  const float* Wv = (const float*)d_in[4];
  const float* Wo = (const float*)d_in[5];
  const float* bo = (const float*)d_in[6];
  float* out = (float*)d_out;

  const size_t NA = (size_t)B_ * S_ * D_;  // 4 Mi elems
  const size_t NW = (size_t)D_ * D_;       // 1 Mi elems
  unsigned short* ws  = (unsigned short*)d_ws;
  unsigned short* qb  = ws;
  unsigned short* cb  = qb + NA;
  unsigned short* WqT = cb + NA;
  unsigned short* WkT = WqT + NW;
  unsigned short* WvT = WkT + NW;
  unsigned short* WoT = WvT + NW;
  unsigned short* qp  = WoT + NW;
  unsigned short* kp  = qp + NA;
  unsigned short* vt  = kp + NA;           // V^T [1024][4096]
  unsigned short* ao  = qb;                // reuse qb after projections

  prep_kernel<<<12288, 256, 0, stream>>>(query, context, Wq, Wk, Wv, Wo,
                                         qb, cb, WqT, WkT, WvT, WoT);
  gemm_qkv<<<768, 256, 0, stream>>>(qb, cb, WqT, WkT, WvT, qp, kp, vt);
  attn_kernel<<<512, 256, 0, stream>>>(qp, kp, vt, ao);
  gemm_out<<<256, 256, 0, stream>>>(ao, WoT, bo, out);
}